// Round 15
// baseline (144.303 us; speedup 1.0000x reference)
//
#include <hip/hip_runtime.h>
#include <hip/hip_fp16.h>
#include <stdint.h>

#define BATCH 4096
#define N_IN  512
#define H1    1536
#define H2    1536
#define N_OUT 512
#define FAN   32
#define E0 (H1 * FAN)
#define E1 (H2 * FAN)
#define E2 (N_OUT * FAN)
#define ETOT (E0 + E1 + E2)
#define EBLK (ETOT / 256)      // 448 build blocks
#define MAXDEG 128             // slot capacity (Poisson(32), max ~54 measured)
#define NN_TAB (H2 + N_OUT)    // 2048 slotted nodes (L2 + L3)

// ---- workspace layout (bytes), total 37,232,640 (< 37,238,784 proven R0) ----
// nvN   : node-major [4096][4096] fp16 = 33,554,432
//         rows 0..511 x^T | 512..2047 h1 | 2048..3583 h2 | (3584..4095 unused)
// W0    : dense [H1][N_IN] fp16 = 1,572,864           (level-1 GEMM weights)
// cnt   : NN_TAB ints = 8,192                          (slotted-edge counters)
// edges : [NN_TAB][MAXDEG] int2 = 2,097,152            (L2+L3 gather edges)
#define OFF_W0  33554432
#define OFF_CNT (OFF_W0 + 1572864)        // 35,127,296 (W0+cnt contiguous: 1 memset)
#define OFF_EDG (OFF_CNT + NN_TAB * 4)    // 35,135,488

typedef _Float16 f16x8 __attribute__((ext_vector_type(8)));
typedef float    f32x4 __attribute__((ext_vector_type(4)));

#define GLL(SRC, DST)                                                        \
    __builtin_amdgcn_global_load_lds(                                        \
        (const __attribute__((address_space(1))) void*)(const void*)(SRC),   \
        (__attribute__((address_space(3))) void*)(void*)(DST), 16, 0, 0)

// ---------- fp16 scatter-add (CAS; duplicates accumulate) — proven ----------
__device__ __forceinline__ void atomic_add_half(__half* addr, float val) {
    uint32_t* base = (uint32_t*)((size_t)addr & ~(size_t)3);
    const bool hi  = ((size_t)addr & 2) != 0;
    uint32_t old = *base, assumed;
    do {
        assumed = old;
        __half2 h2 = *(__half2*)&assumed;
        float f = (hi ? __high2float(h2) : __low2float(h2)) + val;
        __half2 nh = hi ? __halves2half2(__low2half(h2), __float2half_rn(f))
                        : __halves2half2(__float2half_rn(f), __high2half(h2));
        old = atomicCAS(base, assumed, *(uint32_t*)&nh);
    } while (old != assumed);
}

// ---------- fused: {W0 atomics + L2/L3 edge fill} ∥ {x -> x^T node-major} — R14-proven ----------
__global__ __launch_bounds__(256) void k_build(
        const int* __restrict__ s0, const int* __restrict__ d0, const float* __restrict__ w0,
        const int* __restrict__ s1, const int* __restrict__ d1, const float* __restrict__ w1,
        const int* __restrict__ s2, const int* __restrict__ d2, const float* __restrict__ w2,
        __half* __restrict__ W0d, int* __restrict__ cnt, int2* __restrict__ edges,
        const float* __restrict__ x, __half* __restrict__ xT) {
    __shared__ float tile[32][33];
    const int b   = blockIdx.x;
    const int tid = threadIdx.x;
    if (b < EBLK) {
        const int e = b * 256 + tid;
        if (e < E0) {
            atomic_add_half(W0d + (size_t)d0[e] * N_IN + s0[e], w0[e]);
            return;
        }
        int src, node; float w;
        if (e < E0 + E1) { const int i = e - E0;      src = s1[i]; node = d1[i];       w = w1[i]; }
        else             { const int i = e - E0 - E1; src = s2[i]; node = H2 + d2[i];  w = w2[i]; }
        const int pos = atomicAdd(&cnt[node], 1);
        if (pos < MAXDEG) edges[node * MAXDEG + pos] = make_int2(src, __float_as_int(w));
        return;
    }
    // transpose tile t: bb = batch-tile (XCD-swizzled), nt = node-tile
    const int t  = b - EBLK;                    // 0..2047
    const int bb = (t & 7) * 16 + ((t >> 3) & 15);
    const int nt = t >> 7;
    const int n0 = nt * 32;
    const int b0 = bb * 32;
    const int tx = tid & 31, ty = tid >> 5;     // 32 x 8
#pragma unroll
    for (int k = 0; k < 32; k += 8)
        tile[ty + k][tx] = x[(size_t)(b0 + ty + k) * N_IN + (n0 + tx)];
    __syncthreads();
#pragma unroll
    for (int k = 0; k < 32; k += 8)
        xT[(size_t)(n0 + ty + k) * BATCH + (b0 + tx)] = __float2half_rn(tile[tx][ty + k]);
}

// ---------- level-1 GEMM — byte-identical to R14 (proven) ----------
__global__ __launch_bounds__(256, 2)
void k_gemm1(const __half* __restrict__ W0d,   // [H1][512]
             const float* __restrict__ x,      // [4096][512] fp32
             __half* __restrict__ nvh) {       // nvN base (halfs)
    __shared__ __half lA[2][96 * 64];
    __shared__ __half lB[2][128 * 64];
    const int tid  = threadIdx.x;
    const int lane = tid & 63;
    const int wv   = tid >> 6;
    const int wr   = wv >> 1, wc = wv & 1;
    const int m0   = blockIdx.y * 96;
    const int bx   = blockIdx.x;
    const int bt   = (bx & 7) * 4 + (bx >> 3);  // XCD-matched batch-tile
    const int n0   = bt * 128;
    const int lrow = lane >> 3;
    const int lchk = lane & 7;
    const int brow = tid >> 4;       // B-stage: row-in-16-group
    const int bl16 = tid & 15;       // B-stage: 16 lanes cover 64 k (4 fp32 each)

    f32x4 acc[3][4] = {};
    float4 breg[8];

#define ADMA(BUF, KT) {                                                      \
    _Pragma("unroll")                                                        \
    for (int it = 0; it < 3; ++it) {                                         \
        const int row = it * 32 + wv * 8 + lrow;                             \
        const int sc  = lchk ^ (row & 7);                                    \
        GLL(W0d + (size_t)(m0 + row) * N_IN + (KT) + sc * 8,                 \
            lA[BUF] + (it * 32 + wv * 8) * 64);                              \
    }                                                                        \
}
#define BLOAD(KT) {                                                          \
    _Pragma("unroll")                                                        \
    for (int it = 0; it < 8; ++it) {                                         \
        const int r = it * 16 + brow;                                        \
        breg[it] = *(const float4*)(x + (size_t)(n0 + r) * N_IN + (KT) + bl16 * 4); \
    }                                                                        \
}
#define BWRITE(BUF) {                                                        \
    _Pragma("unroll")                                                        \
    for (int it = 0; it < 8; ++it) {                                         \
        const int r    = it * 16 + brow;                                     \
        const int byte = r * 128 + (((bl16 >> 1) ^ (r & 7)) * 16) + ((bl16 & 1) * 8); \
        const __half2 h01 = __floats2half2_rn(breg[it].x, breg[it].y);       \
        const __half2 h23 = __floats2half2_rn(breg[it].z, breg[it].w);       \
        uint2 u; u.x = *(const uint32_t*)&h01; u.y = *(const uint32_t*)&h23; \
        *(uint2*)((char*)&lB[BUF][0] + byte) = u;                            \
    }                                                                        \
}

    const int NT = N_IN >> 6;   // 8
    BLOAD(0)
    ADMA(0, 0)
    asm volatile("s_waitcnt vmcnt(3)" ::: "memory");
    __builtin_amdgcn_sched_barrier(0);
    BWRITE(0)

    int cur = 0;
    for (int t = 0; t < NT; ++t) {
        __builtin_amdgcn_s_barrier();            // prev compute done: overwrite safe
        __builtin_amdgcn_sched_barrier(0);
        if (t + 1 < NT) {
            BLOAD((t + 1) << 6)
            ADMA(cur ^ 1, (t + 1) << 6)
            asm volatile("s_waitcnt vmcnt(3)" ::: "memory");  // B(t+1)+A(t) done; A(t+1) flies
            __builtin_amdgcn_sched_barrier(0);
            BWRITE(cur ^ 1)
        } else {
            asm volatile("s_waitcnt vmcnt(0)" ::: "memory");
        }
        asm volatile("s_waitcnt lgkmcnt(0)" ::: "memory");    // own ds_writes committed
        __builtin_amdgcn_sched_barrier(0);
        __builtin_amdgcn_s_barrier();            // all waves' tile-t data visible
        __builtin_amdgcn_sched_barrier(0);
#pragma unroll
        for (int kk = 0; kk < 2; ++kk) {
            f16x8 af[3], bf[4];
#pragma unroll
            for (int fm = 0; fm < 3; ++fm) {
                const int row = wr * 48 + fm * 16 + (lane & 15);
                const int ch  = (kk * 4 + (lane >> 4)) ^ (row & 7);
                af[fm] = *(const f16x8*)(lA[cur] + row * 64 + ch * 8);
            }
#pragma unroll
            for (int fn = 0; fn < 4; ++fn) {
                const int row = wc * 64 + fn * 16 + (lane & 15);
                const int ch  = (kk * 4 + (lane >> 4)) ^ (row & 7);
                bf[fn] = *(const f16x8*)(lB[cur] + row * 64 + ch * 8);
            }
#pragma unroll
            for (int fm = 0; fm < 3; ++fm)
#pragma unroll
                for (int fn = 0; fn < 4; ++fn)
                    acc[fm][fn] = __builtin_amdgcn_mfma_f32_16x16x32_f16(
                        af[fm], bf[fn], acc[fm][fn], 0, 0, 0);
        }
        cur ^= 1;
    }
#undef BWRITE
#undef BLOAD
#undef ADMA

    // epilogue: relu + node-major store. D map: col=lane&15 (batch), row=(lane>>4)*4+j (node)
    const int cm = (lane >> 4) << 2;
    const int cn = lane & 15;
#pragma unroll
    for (int fm = 0; fm < 3; ++fm)
#pragma unroll
        for (int fn = 0; fn < 4; ++fn) {
            const f32x4 v = acc[fm][fn];
            const int mm = m0 + wr * 48 + fm * 16 + cm;   // h1 node index
            const int nn = n0 + wc * 64 + fn * 16 + cn;   // batch index
#pragma unroll
            for (int j = 0; j < 4; ++j)
                nvh[(size_t)(N_IN + mm + j) * BATCH + nn] =
                    __float2half_rn(fmaxf(v[j], 0.f));
        }
}

// ---------- gather level kernel (L2) — byte-identical to R2/R14 (proven) ----------
__global__ __launch_bounds__(256, 8)
void k_level(const int2* __restrict__ edges,   // pre-offset: table base * MAXDEG
             const int* __restrict__ cnt,      // pre-offset: table node base
             const uint4* __restrict__ nv,     // 512 uint4 per node row (fp16 x8)
             uint4* __restrict__ outb) {       // pre-offset row base (uint4 units)
    const int lane = threadIdx.x & 63;
    const int wv   = threadIdx.x >> 6;
    const int node = __builtin_amdgcn_readfirstlane((blockIdx.y << 2) | wv);
    const int col8 = (blockIdx.x << 6) | lane;  // uint4 index in row, 0..511

    int c = cnt[node];
    c = (c < 0) ? 0 : (c > MAXDEG ? MAXDEG : c);

    float a0 = 0.f, a1 = 0.f, a2 = 0.f, a3 = 0.f, a4 = 0.f, a5 = 0.f, a6 = 0.f, a7 = 0.f;

#define ACC8(q, W) {                                                    \
    const __half2 h0 = *(const __half2*)&(q).x;                         \
    const __half2 h1 = *(const __half2*)&(q).y;                         \
    const __half2 h2 = *(const __half2*)&(q).z;                         \
    const __half2 h3 = *(const __half2*)&(q).w;                         \
    a0 = fmaf(__low2float(h0),  (W), a0);                               \
    a1 = fmaf(__high2float(h0), (W), a1);                               \
    a2 = fmaf(__low2float(h1),  (W), a2);                               \
    a3 = fmaf(__high2float(h1), (W), a3);                               \
    a4 = fmaf(__low2float(h2),  (W), a4);                               \
    a5 = fmaf(__high2float(h2), (W), a5);                               \
    a6 = fmaf(__low2float(h3),  (W), a6);                               \
    a7 = fmaf(__high2float(h3), (W), a7); }

    for (int base = 0; base < c; base += 64) {
        const int2 my = edges[(size_t)node * MAXDEG + base + lane];
        const int m = (c - base < 64) ? (c - base) : 64;
        int j = 0;
        for (; j + 4 <= m; j += 4) {
            const int   s0i = __builtin_amdgcn_readlane(my.x, j)     & 4095;
            const int   s1i = __builtin_amdgcn_readlane(my.x, j + 1) & 4095;
            const int   s2i = __builtin_amdgcn_readlane(my.x, j + 2) & 4095;
            const int   s3i = __builtin_amdgcn_readlane(my.x, j + 3) & 4095;
            const float wa  = __int_as_float(__builtin_amdgcn_readlane(my.y, j));
            const float wb  = __int_as_float(__builtin_amdgcn_readlane(my.y, j + 1));
            const float wc_ = __int_as_float(__builtin_amdgcn_readlane(my.y, j + 2));
            const float wd  = __int_as_float(__builtin_amdgcn_readlane(my.y, j + 3));
            const uint4 q0 = nv[((size_t)s0i << 9) | col8];
            const uint4 q1 = nv[((size_t)s1i << 9) | col8];
            const uint4 q2 = nv[((size_t)s2i << 9) | col8];
            const uint4 q3 = nv[((size_t)s3i << 9) | col8];
            ACC8(q0, wa);
            ACC8(q1, wb);
            ACC8(q2, wc_);
            ACC8(q3, wd);
        }
        for (; j < m; ++j) {
            const int   s0i = __builtin_amdgcn_readlane(my.x, j) & 4095;
            const float wa  = __int_as_float(__builtin_amdgcn_readlane(my.y, j));
            const uint4 q0 = nv[((size_t)s0i << 9) | col8];
            ACC8(q0, wa);
        }
    }

    a0 = fmaxf(a0, 0.f); a1 = fmaxf(a1, 0.f); a2 = fmaxf(a2, 0.f); a3 = fmaxf(a3, 0.f);
    a4 = fmaxf(a4, 0.f); a5 = fmaxf(a5, 0.f); a6 = fmaxf(a6, 0.f); a7 = fmaxf(a7, 0.f);

    const __half2 h0 = __floats2half2_rn(a0, a1);
    const __half2 h1 = __floats2half2_rn(a2, a3);
    const __half2 h2 = __floats2half2_rn(a4, a5);
    const __half2 h3 = __floats2half2_rn(a6, a7);
    uint4 p;
    p.x = *(const uint32_t*)&h0; p.y = *(const uint32_t*)&h1;
    p.z = *(const uint32_t*)&h2; p.w = *(const uint32_t*)&h3;
    outb[((size_t)node << 9) | col8] = p;
}

// ---------- L3 gather with FUSED output: writes d_out [B][N_OUT] fp32 directly ----------
// Same gather body as k_level; epilogue stores the 8 per-thread batch values as
// scalar fp32 dwords at out[(col8*8+k)*N_OUT + node] (stride 2KB). Replaces the
// node-major fp16 write + separate transpose dispatch; also drops one fp16
// quantization of the final level (f32 acc -> f32 out). Scattered 4B stores
// merge to full lines in L2 (adjacent nodes of the same batch row are written
// by neighboring waves); out = 8 MB total.
__global__ __launch_bounds__(256, 8)
void k_level_out(const int2* __restrict__ edges,  // pre-offset: L3 table base
                 const int* __restrict__ cnt,     // pre-offset: L3 node base
                 const uint4* __restrict__ nv,
                 float* __restrict__ out) {       // [BATCH][N_OUT] fp32
    const int lane = threadIdx.x & 63;
    const int wv   = threadIdx.x >> 6;
    const int node = __builtin_amdgcn_readfirstlane((blockIdx.y << 2) | wv);
    const int col8 = (blockIdx.x << 6) | lane;  // uint4 index in row, 0..511

    int c = cnt[node];
    c = (c < 0) ? 0 : (c > MAXDEG ? MAXDEG : c);

    float a0 = 0.f, a1 = 0.f, a2 = 0.f, a3 = 0.f, a4 = 0.f, a5 = 0.f, a6 = 0.f, a7 = 0.f;

    for (int base = 0; base < c; base += 64) {
        const int2 my = edges[(size_t)node * MAXDEG + base + lane];
        const int m = (c - base < 64) ? (c - base) : 64;
        int j = 0;
        for (; j + 4 <= m; j += 4) {
            const int   s0i = __builtin_amdgcn_readlane(my.x, j)     & 4095;
            const int   s1i = __builtin_amdgcn_readlane(my.x, j + 1) & 4095;
            const int   s2i = __builtin_amdgcn_readlane(my.x, j + 2) & 4095;
            const int   s3i = __builtin_amdgcn_readlane(my.x, j + 3) & 4095;
            const float wa  = __int_as_float(__builtin_amdgcn_readlane(my.y, j));
            const float wb  = __int_as_float(__builtin_amdgcn_readlane(my.y, j + 1));
            const float wc_ = __int_as_float(__builtin_amdgcn_readlane(my.y, j + 2));
            const float wd  = __int_as_float(__builtin_amdgcn_readlane(my.y, j + 3));
            const uint4 q0 = nv[((size_t)s0i << 9) | col8];
            const uint4 q1 = nv[((size_t)s1i << 9) | col8];
            const uint4 q2 = nv[((size_t)s2i << 9) | col8];
            const uint4 q3 = nv[((size_t)s3i << 9) | col8];
            ACC8(q0, wa);
            ACC8(q1, wb);
            ACC8(q2, wc_);
            ACC8(q3, wd);
        }
        for (; j < m; ++j) {
            const int   s0i = __builtin_amdgcn_readlane(my.x, j) & 4095;
            const float wa  = __int_as_float(__builtin_amdgcn_readlane(my.y, j));
            const uint4 q0 = nv[((size_t)s0i << 9) | col8];
            ACC8(q0, wa);
        }
    }
#undef ACC8

    // fused epilogue: relu + direct batch-major fp32 stores
    const int b0 = col8 << 3;
    float* o = out + (size_t)b0 * N_OUT + node;
    o[0 * N_OUT] = fmaxf(a0, 0.f);
    o[1 * N_OUT] = fmaxf(a1, 0.f);
    o[2 * N_OUT] = fmaxf(a2, 0.f);
    o[3 * N_OUT] = fmaxf(a3, 0.f);
    o[4 * N_OUT] = fmaxf(a4, 0.f);
    o[5 * N_OUT] = fmaxf(a5, 0.f);
    o[6 * N_OUT] = fmaxf(a6, 0.f);
    o[7 * N_OUT] = fmaxf(a7, 0.f);
}

extern "C" void kernel_launch(void* const* d_in, const int* in_sizes, int n_in,
                              void* d_out, int out_size, void* d_ws, size_t ws_size,
                              hipStream_t stream) {
    const float* x  = (const float*)d_in[0];
    const int* s0   = (const int*)d_in[1];
    const int* dd0  = (const int*)d_in[2];
    const float* w0 = (const float*)d_in[3];
    const int* s1   = (const int*)d_in[4];
    const int* dd1  = (const int*)d_in[5];
    const float* w1 = (const float*)d_in[6];
    const int* s2   = (const int*)d_in[7];
    const int* dd2  = (const int*)d_in[8];
    const float* w2 = (const float*)d_in[9];

    char*     ws    = (char*)d_ws;
    __half*   nvh   = (__half*)ws;                   // node-major fp16 rows
    uint4*    nv4   = (uint4*)ws;
    __half*   W0p   = (__half*)(ws + OFF_W0);
    int*      cnt   = (int*)(ws + OFF_CNT);
    int2*     edges = (int2*)(ws + OFF_EDG);

    // zero W0 + cnt (contiguous region, one memset)
    hipMemsetAsync(W0p, 0, (size_t)1572864 + NN_TAB * 4, stream);

    // fused build: {W0 atomics + L2/L3 edges} || {x -> x^T node-major}
    k_build<<<EBLK + 2048, 256, 0, stream>>>(s0, dd0, w0, s1, dd1, w1, s2, dd2, w2,
                                             W0p, cnt, edges, x, nvh);

    // level 1 = GEMM (B = x fp32 direct), output node-major rows 512..2047
    k_gemm1<<<dim3(BATCH / 128, H1 / 96), 256, 0, stream>>>(W0p, x, nvh);

    // level 2 = gather (table nodes 0..1535), output rows 2048..3583
    k_level<<<dim3(8, H2 / 4), 256, 0, stream>>>(edges, cnt, nv4,
                                                 nv4 + (size_t)(N_IN + H1) * 512);

    // level 3 = gather (table nodes 1536..2047) with fused batch-major fp32 output
    k_level_out<<<dim3(8, N_OUT / 4), 256, 0, stream>>>(edges + (size_t)H2 * MAXDEG,
                                                        cnt + H2, nv4, (float*)d_out);
}

// Round 16
// 137.757 us; speedup vs baseline: 1.0475x; 1.0475x over previous
//
#include <hip/hip_runtime.h>
#include <hip/hip_fp16.h>
#include <stdint.h>

#define BATCH 4096
#define N_IN  512
#define H1    1536
#define H2    1536
#define N_OUT 512
#define FAN   32
#define E0 (H1 * FAN)
#define E1 (H2 * FAN)
#define E2 (N_OUT * FAN)
#define ETOT (E0 + E1 + E2)
#define EBLK (ETOT / 256)      // 448 build blocks
#define MAXDEG 128             // slot capacity (Poisson(32), max ~54 measured)
#define NN_TAB (H2 + N_OUT)    // 2048 slotted nodes (L2 + L3)

// ---- workspace layout (bytes), total 37,232,640 (< 37,238,784 proven R0) ----
// nvN   : node-major [4096][4096] fp16 = 33,554,432
//         rows 0..511 x^T | 512..2047 h1 | 2048..3583 h2 | 3584..4095 out^T
// W0    : dense [H1][N_IN] fp16 = 1,572,864           (level-1 GEMM weights)
// cnt   : NN_TAB ints = 8,192                          (slotted-edge counters)
// edges : [NN_TAB][MAXDEG] int2 = 2,097,152            (L2+L3 gather edges)
#define OFF_W0  33554432
#define OFF_CNT (OFF_W0 + 1572864)        // 35,127,296 (W0+cnt contiguous: 1 memset)
#define OFF_EDG (OFF_CNT + NN_TAB * 4)    // 35,135,488

typedef _Float16 f16x8 __attribute__((ext_vector_type(8)));
typedef float    f32x4 __attribute__((ext_vector_type(4)));

#define GLL(SRC, DST)                                                        \
    __builtin_amdgcn_global_load_lds(                                        \
        (const __attribute__((address_space(1))) void*)(const void*)(SRC),   \
        (__attribute__((address_space(3))) void*)(void*)(DST), 16, 0, 0)

// ---------- fp16 scatter-add (CAS; duplicates accumulate) — proven ----------
__device__ __forceinline__ void atomic_add_half(__half* addr, float val) {
    uint32_t* base = (uint32_t*)((size_t)addr & ~(size_t)3);
    const bool hi  = ((size_t)addr & 2) != 0;
    uint32_t old = *base, assumed;
    do {
        assumed = old;
        __half2 h2 = *(__half2*)&assumed;
        float f = (hi ? __high2float(h2) : __low2float(h2)) + val;
        __half2 nh = hi ? __halves2half2(__low2half(h2), __float2half_rn(f))
                        : __halves2half2(__float2half_rn(f), __high2half(h2));
        old = atomicCAS(base, assumed, *(uint32_t*)&nh);
    } while (old != assumed);
}

// ---------- fused: {W0 atomics + L2/L3 edge fill} ∥ {x -> x^T node-major} ----------
// Blocks 0..447: edge/W0 build. Blocks 448..2495: 32x32 transpose tiles.
// Disjoint outputs, no ordering needed within the dispatch. Transpose
// batch-tile mapping is XCD-swizzled so the batch slice [c*512,+512) lands on
// XCD c — matching the L2 gather's col-tile c reader.
__global__ __launch_bounds__(256) void k_build(
        const int* __restrict__ s0, const int* __restrict__ d0, const float* __restrict__ w0,
        const int* __restrict__ s1, const int* __restrict__ d1, const float* __restrict__ w1,
        const int* __restrict__ s2, const int* __restrict__ d2, const float* __restrict__ w2,
        __half* __restrict__ W0d, int* __restrict__ cnt, int2* __restrict__ edges,
        const float* __restrict__ x, __half* __restrict__ xT) {
    __shared__ float tile[32][33];
    const int b   = blockIdx.x;
    const int tid = threadIdx.x;
    if (b < EBLK) {
        const int e = b * 256 + tid;
        if (e < E0) {
            atomic_add_half(W0d + (size_t)d0[e] * N_IN + s0[e], w0[e]);
            return;
        }
        int src, node; float w;
        if (e < E0 + E1) { const int i = e - E0;      src = s1[i]; node = d1[i];       w = w1[i]; }
        else             { const int i = e - E0 - E1; src = s2[i]; node = H2 + d2[i];  w = w2[i]; }
        const int pos = atomicAdd(&cnt[node], 1);
        if (pos < MAXDEG) edges[node * MAXDEG + pos] = make_int2(src, __float_as_int(w));
        return;
    }
    // transpose tile t: bb = batch-tile (XCD-swizzled), nt = node-tile
    const int t  = b - EBLK;                    // 0..2047
    const int bb = (t & 7) * 16 + ((t >> 3) & 15);
    const int nt = t >> 7;
    const int n0 = nt * 32;
    const int b0 = bb * 32;
    const int tx = tid & 31, ty = tid >> 5;     // 32 x 8
#pragma unroll
    for (int k = 0; k < 32; k += 8)
        tile[ty + k][tx] = x[(size_t)(b0 + ty + k) * N_IN + (n0 + tx)];
    __syncthreads();
#pragma unroll
    for (int k = 0; k < 32; k += 8)
        xT[(size_t)(n0 + ty + k) * BATCH + (b0 + tx)] = __float2half_rn(tile[tx][ty + k]);
}

// ---------- level-1 GEMM: h1[m][b] = relu(sum_k W0[m][k] x[b][k]) ----------
// BM=96 BN=128 BK=64, 256 thr, dbuf, counted vmcnt. A=W0 GLL chunk-XOR;
// B=x fp32 reg-staged + swizzled ds_write; node-major scatter epilogue;
// batch-tile XCD-swizzle matches the L2 gather's reader.
__global__ __launch_bounds__(256, 2)
void k_gemm1(const __half* __restrict__ W0d,   // [H1][512]
             const float* __restrict__ x,      // [4096][512] fp32
             __half* __restrict__ nvh) {       // nvN base (halfs)
    __shared__ __half lA[2][96 * 64];
    __shared__ __half lB[2][128 * 64];
    const int tid  = threadIdx.x;
    const int lane = tid & 63;
    const int wv   = tid >> 6;
    const int wr   = wv >> 1, wc = wv & 1;
    const int m0   = blockIdx.y * 96;
    const int bx   = blockIdx.x;
    const int bt   = (bx & 7) * 4 + (bx >> 3);  // XCD-matched batch-tile
    const int n0   = bt * 128;
    const int lrow = lane >> 3;
    const int lchk = lane & 7;
    const int brow = tid >> 4;       // B-stage: row-in-16-group
    const int bl16 = tid & 15;       // B-stage: 16 lanes cover 64 k (4 fp32 each)

    f32x4 acc[3][4] = {};
    float4 breg[8];

#define ADMA(BUF, KT) {                                                      \
    _Pragma("unroll")                                                        \
    for (int it = 0; it < 3; ++it) {                                         \
        const int row = it * 32 + wv * 8 + lrow;                             \
        const int sc  = lchk ^ (row & 7);                                    \
        GLL(W0d + (size_t)(m0 + row) * N_IN + (KT) + sc * 8,                 \
            lA[BUF] + (it * 32 + wv * 8) * 64);                              \
    }                                                                        \
}
#define BLOAD(KT) {                                                          \
    _Pragma("unroll")                                                        \
    for (int it = 0; it < 8; ++it) {                                         \
        const int r = it * 16 + brow;                                        \
        breg[it] = *(const float4*)(x + (size_t)(n0 + r) * N_IN + (KT) + bl16 * 4); \
    }                                                                        \
}
#define BWRITE(BUF) {                                                        \
    _Pragma("unroll")                                                        \
    for (int it = 0; it < 8; ++it) {                                         \
        const int r    = it * 16 + brow;                                     \
        const int byte = r * 128 + (((bl16 >> 1) ^ (r & 7)) * 16) + ((bl16 & 1) * 8); \
        const __half2 h01 = __floats2half2_rn(breg[it].x, breg[it].y);       \
        const __half2 h23 = __floats2half2_rn(breg[it].z, breg[it].w);       \
        uint2 u; u.x = *(const uint32_t*)&h01; u.y = *(const uint32_t*)&h23; \
        *(uint2*)((char*)&lB[BUF][0] + byte) = u;                            \
    }                                                                        \
}

    const int NT = N_IN >> 6;   // 8
    BLOAD(0)
    ADMA(0, 0)
    asm volatile("s_waitcnt vmcnt(3)" ::: "memory");
    __builtin_amdgcn_sched_barrier(0);
    BWRITE(0)

    int cur = 0;
    for (int t = 0; t < NT; ++t) {
        __builtin_amdgcn_s_barrier();            // prev compute done: overwrite safe
        __builtin_amdgcn_sched_barrier(0);
        if (t + 1 < NT) {
            BLOAD((t + 1) << 6)
            ADMA(cur ^ 1, (t + 1) << 6)
            asm volatile("s_waitcnt vmcnt(3)" ::: "memory");  // B(t+1)+A(t) done; A(t+1) flies
            __builtin_amdgcn_sched_barrier(0);
            BWRITE(cur ^ 1)
        } else {
            asm volatile("s_waitcnt vmcnt(0)" ::: "memory");
        }
        asm volatile("s_waitcnt lgkmcnt(0)" ::: "memory");    // own ds_writes committed
        __builtin_amdgcn_sched_barrier(0);
        __builtin_amdgcn_s_barrier();            // all waves' tile-t data visible
        __builtin_amdgcn_sched_barrier(0);
#pragma unroll
        for (int kk = 0; kk < 2; ++kk) {
            f16x8 af[3], bf[4];
#pragma unroll
            for (int fm = 0; fm < 3; ++fm) {
                const int row = wr * 48 + fm * 16 + (lane & 15);
                const int ch  = (kk * 4 + (lane >> 4)) ^ (row & 7);
                af[fm] = *(const f16x8*)(lA[cur] + row * 64 + ch * 8);
            }
#pragma unroll
            for (int fn = 0; fn < 4; ++fn) {
                const int row = wc * 64 + fn * 16 + (lane & 15);
                const int ch  = (kk * 4 + (lane >> 4)) ^ (row & 7);
                bf[fn] = *(const f16x8*)(lB[cur] + row * 64 + ch * 8);
            }
#pragma unroll
            for (int fm = 0; fm < 3; ++fm)
#pragma unroll
                for (int fn = 0; fn < 4; ++fn)
                    acc[fm][fn] = __builtin_amdgcn_mfma_f32_16x16x32_f16(
                        af[fm], bf[fn], acc[fm][fn], 0, 0, 0);
        }
        cur ^= 1;
    }
#undef BWRITE
#undef BLOAD
#undef ADMA

    // epilogue: relu + node-major store. D map: col=lane&15 (batch), row=(lane>>4)*4+j (node)
    const int cm = (lane >> 4) << 2;
    const int cn = lane & 15;
#pragma unroll
    for (int fm = 0; fm < 3; ++fm)
#pragma unroll
        for (int fn = 0; fn < 4; ++fn) {
            const f32x4 v = acc[fm][fn];
            const int mm = m0 + wr * 48 + fm * 16 + cm;   // h1 node index
            const int nn = n0 + wc * 64 + fn * 16 + cn;   // batch index
#pragma unroll
            for (int j = 0; j < 4; ++j)
                nvh[(size_t)(N_IN + mm + j) * BATCH + nn] =
                    __float2half_rn(fmaxf(v[j], 0.f));
        }
}

// ---------- gather level kernel — byte-identical to R2 (proven base) ----------
__global__ __launch_bounds__(256, 8)
void k_level(const int2* __restrict__ edges,   // pre-offset: table base * MAXDEG
             const int* __restrict__ cnt,      // pre-offset: table node base
             const uint4* __restrict__ nv,     // 512 uint4 per node row (fp16 x8)
             uint4* __restrict__ outb) {       // pre-offset row base (uint4 units)
    const int lane = threadIdx.x & 63;
    const int wv   = threadIdx.x >> 6;
    const int node = __builtin_amdgcn_readfirstlane((blockIdx.y << 2) | wv);
    const int col8 = (blockIdx.x << 6) | lane;  // uint4 index in row, 0..511

    int c = cnt[node];
    c = (c < 0) ? 0 : (c > MAXDEG ? MAXDEG : c);

    float a0 = 0.f, a1 = 0.f, a2 = 0.f, a3 = 0.f, a4 = 0.f, a5 = 0.f, a6 = 0.f, a7 = 0.f;

#define ACC8(q, W) {                                                    \
    const __half2 h0 = *(const __half2*)&(q).x;                         \
    const __half2 h1 = *(const __half2*)&(q).y;                         \
    const __half2 h2 = *(const __half2*)&(q).z;                         \
    const __half2 h3 = *(const __half2*)&(q).w;                         \
    a0 = fmaf(__low2float(h0),  (W), a0);                               \
    a1 = fmaf(__high2float(h0), (W), a1);                               \
    a2 = fmaf(__low2float(h1),  (W), a2);                               \
    a3 = fmaf(__high2float(h1), (W), a3);                               \
    a4 = fmaf(__low2float(h2),  (W), a4);                               \
    a5 = fmaf(__high2float(h2), (W), a5);                               \
    a6 = fmaf(__low2float(h3),  (W), a6);                               \
    a7 = fmaf(__high2float(h3), (W), a7); }

    for (int base = 0; base < c; base += 64) {
        const int2 my = edges[(size_t)node * MAXDEG + base + lane];
        const int m = (c - base < 64) ? (c - base) : 64;
        int j = 0;
        for (; j + 4 <= m; j += 4) {
            const int   s0i = __builtin_amdgcn_readlane(my.x, j)     & 4095;
            const int   s1i = __builtin_amdgcn_readlane(my.x, j + 1) & 4095;
            const int   s2i = __builtin_amdgcn_readlane(my.x, j + 2) & 4095;
            const int   s3i = __builtin_amdgcn_readlane(my.x, j + 3) & 4095;
            const float wa  = __int_as_float(__builtin_amdgcn_readlane(my.y, j));
            const float wb  = __int_as_float(__builtin_amdgcn_readlane(my.y, j + 1));
            const float wc_ = __int_as_float(__builtin_amdgcn_readlane(my.y, j + 2));
            const float wd  = __int_as_float(__builtin_amdgcn_readlane(my.y, j + 3));
            const uint4 q0 = nv[((size_t)s0i << 9) | col8];
            const uint4 q1 = nv[((size_t)s1i << 9) | col8];
            const uint4 q2 = nv[((size_t)s2i << 9) | col8];
            const uint4 q3 = nv[((size_t)s3i << 9) | col8];
            ACC8(q0, wa);
            ACC8(q1, wb);
            ACC8(q2, wc_);
            ACC8(q3, wd);
        }
        for (; j < m; ++j) {
            const int   s0i = __builtin_amdgcn_readlane(my.x, j) & 4095;
            const float wa  = __int_as_float(__builtin_amdgcn_readlane(my.y, j));
            const uint4 q0 = nv[((size_t)s0i << 9) | col8];
            ACC8(q0, wa);
        }
    }
#undef ACC8

    a0 = fmaxf(a0, 0.f); a1 = fmaxf(a1, 0.f); a2 = fmaxf(a2, 0.f); a3 = fmaxf(a3, 0.f);
    a4 = fmaxf(a4, 0.f); a5 = fmaxf(a5, 0.f); a6 = fmaxf(a6, 0.f); a7 = fmaxf(a7, 0.f);

    const __half2 h0 = __floats2half2_rn(a0, a1);
    const __half2 h1 = __floats2half2_rn(a2, a3);
    const __half2 h2 = __floats2half2_rn(a4, a5);
    const __half2 h3 = __floats2half2_rn(a6, a7);
    uint4 p;
    p.x = *(const uint32_t*)&h0; p.y = *(const uint32_t*)&h1;
    p.z = *(const uint32_t*)&h2; p.w = *(const uint32_t*)&h3;
    outb[((size_t)node << 9) | col8] = p;
}

// ---------- out^T rows (fp16, [N_OUT][B]) -> d_out [B, N_OUT] fp32 — R0-proven ----------
__global__ __launch_bounds__(256) void k_transpose_out(const __half* __restrict__ outh,
                                                       float* __restrict__ out) {
    __shared__ float tile[32][33];
    const int tx = threadIdx.x, ty = threadIdx.y;   // 32 x 8
    const int n0 = blockIdx.x * 32;
    const int b0 = blockIdx.y * 32;
#pragma unroll
    for (int k = 0; k < 32; k += 8)
        tile[ty + k][tx] = __half2float(outh[(size_t)(n0 + ty + k) * BATCH + (b0 + tx)]);
    __syncthreads();
#pragma unroll
    for (int k = 0; k < 32; k += 8)
        out[(size_t)(b0 + ty + k) * N_OUT + (n0 + tx)] = tile[tx][ty + k];
}

extern "C" void kernel_launch(void* const* d_in, const int* in_sizes, int n_in,
                              void* d_out, int out_size, void* d_ws, size_t ws_size,
                              hipStream_t stream) {
    const float* x  = (const float*)d_in[0];
    const int* s0   = (const int*)d_in[1];
    const int* dd0  = (const int*)d_in[2];
    const float* w0 = (const float*)d_in[3];
    const int* s1   = (const int*)d_in[4];
    const int* dd1  = (const int*)d_in[5];
    const float* w1 = (const float*)d_in[6];
    const int* s2   = (const int*)d_in[7];
    const int* dd2  = (const int*)d_in[8];
    const float* w2 = (const float*)d_in[9];

    char*     ws    = (char*)d_ws;
    __half*   nvh   = (__half*)ws;                   // node-major fp16 rows
    uint4*    nv4   = (uint4*)ws;
    __half*   W0p   = (__half*)(ws + OFF_W0);
    int*      cnt   = (int*)(ws + OFF_CNT);
    int2*     edges = (int2*)(ws + OFF_EDG);

    // zero W0 + cnt (contiguous region, one memset)
    hipMemsetAsync(W0p, 0, (size_t)1572864 + NN_TAB * 4, stream);

    // fused build: {W0 atomics + L2/L3 edges} || {x -> x^T node-major}
    k_build<<<EBLK + 2048, 256, 0, stream>>>(s0, dd0, w0, s1, dd1, w1, s2, dd2, w2,
                                             W0p, cnt, edges, x, nvh);

    // level 1 = GEMM (B = x fp32 direct), output node-major rows 512..2047
    k_gemm1<<<dim3(BATCH / 128, H1 / 96), 256, 0, stream>>>(W0p, x, nvh);

    // level 2 = gather (table nodes 0..1535), output rows 2048..3583
    k_level<<<dim3(8, H2 / 4), 256, 0, stream>>>(edges, cnt, nv4,
                                                 nv4 + (size_t)(N_IN + H1) * 512);

    // level 3 = gather (table nodes 1536..2047), output rows 3584..4095
    k_level<<<dim3(8, N_OUT / 4), 256, 0, stream>>>(edges + (size_t)H2 * MAXDEG, cnt + H2,
                                                    nv4, nv4 + (size_t)(N_IN + H1 + H2) * 512);

    // out^T -> d_out [B, N_OUT] fp32
    k_transpose_out<<<dim3(N_OUT / 32, BATCH / 32), dim3(32, 8), 0, stream>>>(
        (const __half*)(ws + (size_t)(N_IN + H1 + H2) * BATCH * 2), (float*)d_out);
}